// Round 2
// baseline (1639.272 us; speedup 1.0000x reference)
//
#include <hip/hip_runtime.h>

#define NGROUPS 50000
#define NITEMS  100000
#define NNODES  150000
#define NEDGES  2400000
#define DIM     64

// ---------------------------------------------------------------------------
// zero-fill (float4-vectorized)
__global__ __launch_bounds__(256) void k_zero(float4* __restrict__ p, int n4) {
    int i = blockIdx.x * blockDim.x + threadIdx.x;
    int s = gridDim.x * blockDim.x;
    float4 z = make_float4(0.f, 0.f, 0.f, 0.f);
    for (; i < n4; i += s) p[i] = z;
}

// concat groups||items -> x  (all float4 moves, fully coalesced)
__global__ __launch_bounds__(256) void k_concat(const float4* __restrict__ g,
                                                const float4* __restrict__ it,
                                                float4* __restrict__ x) {
    const int n1 = NGROUPS * DIM / 4;
    const int n  = NNODES * DIM / 4;
    int i = blockIdx.x * blockDim.x + threadIdx.x;
    int s = gridDim.x * blockDim.x;
    for (; i < n; i += s) x[i] = (i < n1) ? g[i] : it[i - n1];
}

// COO SpMM: one wave per edge, lane = embedding dim.
// y[row][lane] += val * x[col][lane]   via HW float atomics.
__global__ __launch_bounds__(256) void k_spmm(const int*   __restrict__ rows,
                                              const int*   __restrict__ cols,
                                              const float* __restrict__ vals,
                                              const float* __restrict__ x,
                                              float*       __restrict__ y) {
    int wid  = (blockIdx.x * blockDim.x + threadIdx.x) >> 6;
    int lane = threadIdx.x & 63;
    int nw   = (gridDim.x * blockDim.x) >> 6;
    for (int e = wid; e < NEDGES; e += nw) {
        int   r = rows[e];
        int   c = cols[e];
        float v = vals[e];
        float xv = x[c * DIM + lane];
        unsafeAtomicAdd(&y[r * DIM + lane], v * xv);
    }
}

// out (+)= src over the first NGROUPS rows; first==1 does plain assignment
// so we never need to pre-zero d_out (harness poisons it with 0xAA).
__global__ __launch_bounds__(256) void k_accum(const float4* __restrict__ src,
                                               float4* __restrict__ dst,
                                               int first) {
    const int n = NGROUPS * DIM / 4;
    int i = blockIdx.x * blockDim.x + threadIdx.x;
    int s = gridDim.x * blockDim.x;
    if (first) {
        for (; i < n; i += s) dst[i] = src[i];
    } else {
        for (; i < n; i += s) {
            float4 a = dst[i], b = src[i];
            a.x += b.x; a.y += b.y; a.z += b.z; a.w += b.w;
            dst[i] = a;
        }
    }
}

// out = (out + groups) * 0.25
__global__ __launch_bounds__(256) void k_final(const float4* __restrict__ g,
                                               float4* __restrict__ out) {
    const int n = NGROUPS * DIM / 4;
    int i = blockIdx.x * blockDim.x + threadIdx.x;
    int s = gridDim.x * blockDim.x;
    for (; i < n; i += s) {
        float4 a = out[i], b = g[i];
        out[i] = make_float4((a.x + b.x) * 0.25f, (a.y + b.y) * 0.25f,
                             (a.z + b.z) * 0.25f, (a.w + b.w) * 0.25f);
    }
}

extern "C" void kernel_launch(void* const* d_in, const int* in_sizes, int n_in,
                              void* d_out, int out_size, void* d_ws, size_t ws_size,
                              hipStream_t stream) {
    const float* groups = (const float*)d_in[0];
    const float* items  = (const float*)d_in[1];
    const float* vals   = (const float*)d_in[2];
    const int*   rows   = (const int*)d_in[3];
    const int*   cols   = (const int*)d_in[4];
    float* out = (float*)d_out;

    float* xA = (float*)d_ws;                 // 150000*64 f32 = 38.4 MB
    float* xB = xA + (size_t)NNODES * DIM;    // another 38.4 MB

    dim3 blk(256);

    // x0 = concat(groups, items)
    k_concat<<<2048, blk, 0, stream>>>((const float4*)groups, (const float4*)items,
                                       (float4*)xA);

    for (int l = 0; l < 3; ++l) {
        k_zero<<<2048, blk, 0, stream>>>((float4*)xB, NNODES * DIM / 4);
        k_spmm<<<4096, blk, 0, stream>>>(rows, cols, vals, xA, xB);
        k_accum<<<512, blk, 0, stream>>>((const float4*)xB, (float4*)out, l == 0);
        float* t = xA; xA = xB; xB = t;
    }

    k_final<<<512, blk, 0, stream>>>((const float4*)groups, (float4*)out);
}

// Round 3
// 698.850 us; speedup vs baseline: 2.3457x; 2.3457x over previous
//
#include <hip/hip_runtime.h>

#define NGROUPS 50000
#define NITEMS  100000
#define NNODES  150000
#define NEDGES  2400000
#define DIM     64

// ============================ CSR-gather path ==============================

// zero-fill ints
__global__ __launch_bounds__(256) void k_zero_i(int* __restrict__ p, int n) {
    int i = blockIdx.x * blockDim.x + threadIdx.x;
    int s = gridDim.x * blockDim.x;
    for (; i < n; i += s) p[i] = 0;
}

// histogram of row indices
__global__ __launch_bounds__(256) void k_hist(const int* __restrict__ rows,
                                              int* __restrict__ cnt) {
    int i = blockIdx.x * blockDim.x + threadIdx.x;
    int s = gridDim.x * blockDim.x;
    for (; i < NEDGES; i += s) atomicAdd(&cnt[rows[i]], 1);
}

// per-256-block sums of cnt -> bsum[b]
__global__ __launch_bounds__(256) void k_bsum(const int* __restrict__ cnt,
                                              int* __restrict__ bsum) {
    __shared__ int s[256];
    int t = threadIdx.x;
    int i = blockIdx.x * 256 + t;
    s[t] = (i < NNODES) ? cnt[i] : 0;
    __syncthreads();
    for (int off = 128; off > 0; off >>= 1) {
        if (t < off) s[t] += s[t + off];
        __syncthreads();
    }
    if (t == 0) bsum[blockIdx.x] = s[0];
}

// single-block exclusive scan of bsum (NB <= 1024) -> boff
__global__ __launch_bounds__(1024) void k_scanb(const int* __restrict__ bsum,
                                                int* __restrict__ boff, int nb) {
    __shared__ int s[1024];
    int t = threadIdx.x;
    int v = (t < nb) ? bsum[t] : 0;
    s[t] = v;
    __syncthreads();
    for (int off = 1; off < 1024; off <<= 1) {
        int u = (t >= off) ? s[t - off] : 0;
        __syncthreads();
        s[t] += u;
        __syncthreads();
    }
    if (t < nb) boff[t] = s[t] - v;   // exclusive
}

// rowptr[i] = boff[b] + exclusive_scan_within_block(cnt); also cursor copy
__global__ __launch_bounds__(256) void k_rowptr(const int* __restrict__ cnt,
                                                const int* __restrict__ boff,
                                                int* __restrict__ rowptr,
                                                int* __restrict__ cursor) {
    __shared__ int s[256];
    int t = threadIdx.x;
    int i = blockIdx.x * 256 + t;
    int c = (i < NNODES) ? cnt[i] : 0;
    s[t] = c;
    __syncthreads();
    for (int off = 1; off < 256; off <<= 1) {
        int u = (t >= off) ? s[t - off] : 0;
        __syncthreads();
        s[t] += u;
        __syncthreads();
    }
    int base = boff[blockIdx.x];
    int excl = base + s[t] - c;
    if (i < NNODES) {
        rowptr[i] = excl;
        cursor[i] = excl;
        if (i == NNODES - 1) rowptr[NNODES] = excl + c;   // == NEDGES
    }
}

// permute (col,val) into row-sorted order
__global__ __launch_bounds__(256) void k_scatter(const int* __restrict__ rows,
                                                 const int* __restrict__ cols,
                                                 const float* __restrict__ vals,
                                                 int* __restrict__ cursor,
                                                 int* __restrict__ scol,
                                                 float* __restrict__ sval) {
    int i = blockIdx.x * blockDim.x + threadIdx.x;
    int s = gridDim.x * blockDim.x;
    for (; i < NEDGES; i += s) {
        int r = rows[i];
        int pos = atomicAdd(&cursor[r], 1);
        scol[pos] = cols[i];
        sval[pos] = vals[i];
    }
}

// ---- gather SpMM: one wave per row, lane = dim ----
// LAYER 1: src = groups|items (branch), y = x1, out[r] = acc (r<NGROUPS)
// LAYER 2: src = x1, y = x2, out[r] += acc
// LAYER 3: rows [0,NGROUPS) only; src = x2; out[r] = (out[r]+groups[r]+acc)*.25
template <int LAYER>
__global__ __launch_bounds__(256) void k_spmm_csr(const int* __restrict__ rowptr,
                                                  const int* __restrict__ scol,
                                                  const float* __restrict__ sval,
                                                  const float* __restrict__ groups,
                                                  const float* __restrict__ items,
                                                  const float* __restrict__ xsrc,
                                                  float* __restrict__ y,
                                                  float* __restrict__ out) {
    int r = blockIdx.x * 4 + (threadIdx.x >> 6);
    int lane = threadIdx.x & 63;
    int beg = rowptr[r], end = rowptr[r + 1];

    float acc0 = 0.f, acc1 = 0.f;
    int j = beg;
    for (; j + 2 <= end; j += 2) {
        int c0 = scol[j], c1 = scol[j + 1];
        float v0 = sval[j], v1 = sval[j + 1];
        const float *s0, *s1;
        if (LAYER == 1) {
            s0 = (c0 < NGROUPS) ? groups + (size_t)c0 * DIM
                                : items + (size_t)(c0 - NGROUPS) * DIM;
            s1 = (c1 < NGROUPS) ? groups + (size_t)c1 * DIM
                                : items + (size_t)(c1 - NGROUPS) * DIM;
        } else {
            s0 = xsrc + (size_t)c0 * DIM;
            s1 = xsrc + (size_t)c1 * DIM;
        }
        float g0 = s0[lane], g1 = s1[lane];
        acc0 = fmaf(v0, g0, acc0);
        acc1 = fmaf(v1, g1, acc1);
    }
    if (j < end) {
        int c0 = scol[j];
        float v0 = sval[j];
        const float* s0;
        if (LAYER == 1) {
            s0 = (c0 < NGROUPS) ? groups + (size_t)c0 * DIM
                                : items + (size_t)(c0 - NGROUPS) * DIM;
        } else {
            s0 = xsrc + (size_t)c0 * DIM;
        }
        acc0 = fmaf(v0, s0[lane], acc0);
    }
    float acc = acc0 + acc1;

    size_t o = (size_t)r * DIM + lane;
    if (LAYER == 1) {
        y[o] = acc;
        if (r < NGROUPS) out[o] = acc;
    } else if (LAYER == 2) {
        y[o] = acc;
        if (r < NGROUPS) out[o] += acc;
    } else {
        out[o] = (out[o] + groups[o] + acc) * 0.25f;
    }
}

// ====================== fallback path (atomic scatter) ======================

__global__ __launch_bounds__(256) void k_zero(float4* __restrict__ p, int n4) {
    int i = blockIdx.x * blockDim.x + threadIdx.x;
    int s = gridDim.x * blockDim.x;
    float4 z = make_float4(0.f, 0.f, 0.f, 0.f);
    for (; i < n4; i += s) p[i] = z;
}

__global__ __launch_bounds__(256) void k_concat(const float4* __restrict__ g,
                                                const float4* __restrict__ it,
                                                float4* __restrict__ x) {
    const int n1 = NGROUPS * DIM / 4;
    const int n  = NNODES * DIM / 4;
    int i = blockIdx.x * blockDim.x + threadIdx.x;
    int s = gridDim.x * blockDim.x;
    for (; i < n; i += s) x[i] = (i < n1) ? g[i] : it[i - n1];
}

__global__ __launch_bounds__(256) void k_spmm(const int*   __restrict__ rows,
                                              const int*   __restrict__ cols,
                                              const float* __restrict__ vals,
                                              const float* __restrict__ x,
                                              float*       __restrict__ y) {
    int wid  = (blockIdx.x * blockDim.x + threadIdx.x) >> 6;
    int lane = threadIdx.x & 63;
    int nw   = (gridDim.x * blockDim.x) >> 6;
    for (int e = wid; e < NEDGES; e += nw) {
        int   r = rows[e];
        int   c = cols[e];
        float v = vals[e];
        unsafeAtomicAdd(&y[r * DIM + lane], v * x[c * DIM + lane]);
    }
}

__global__ __launch_bounds__(256) void k_accum(const float4* __restrict__ src,
                                               float4* __restrict__ dst, int first) {
    const int n = NGROUPS * DIM / 4;
    int i = blockIdx.x * blockDim.x + threadIdx.x;
    int s = gridDim.x * blockDim.x;
    if (first) { for (; i < n; i += s) dst[i] = src[i]; }
    else {
        for (; i < n; i += s) {
            float4 a = dst[i], b = src[i];
            a.x += b.x; a.y += b.y; a.z += b.z; a.w += b.w;
            dst[i] = a;
        }
    }
}

__global__ __launch_bounds__(256) void k_final(const float4* __restrict__ g,
                                               float4* __restrict__ out) {
    const int n = NGROUPS * DIM / 4;
    int i = blockIdx.x * blockDim.x + threadIdx.x;
    int s = gridDim.x * blockDim.x;
    for (; i < n; i += s) {
        float4 a = out[i], b = g[i];
        out[i] = make_float4((a.x + b.x) * 0.25f, (a.y + b.y) * 0.25f,
                             (a.z + b.z) * 0.25f, (a.w + b.w) * 0.25f);
    }
}

// ===========================================================================

extern "C" void kernel_launch(void* const* d_in, const int* in_sizes, int n_in,
                              void* d_out, int out_size, void* d_ws, size_t ws_size,
                              hipStream_t stream) {
    const float* groups = (const float*)d_in[0];
    const float* items  = (const float*)d_in[1];
    const float* vals   = (const float*)d_in[2];
    const int*   rows   = (const int*)d_in[3];
    const int*   cols   = (const int*)d_in[4];
    float* out = (float*)d_out;

    const int NB = (NNODES + 255) / 256;              // 586 blocks

    // ws layout (floats)
    size_t off = 0;
    float* x1     = (float*)d_ws;            off += (size_t)NNODES * DIM;   // 9.6M
    float* x2     = (float*)d_ws + off;      off += (size_t)NNODES * DIM;   // 9.6M
    int*   cnt    = (int*)((float*)d_ws + off); off += NNODES;
    int*   rowptr = (int*)((float*)d_ws + off); off += NNODES + 4;
    int*   cursor = (int*)((float*)d_ws + off); off += NNODES;
    int*   bsum   = (int*)((float*)d_ws + off); off += 1024;
    int*   boff   = (int*)((float*)d_ws + off); off += 1024;
    int*   scol   = (int*)((float*)d_ws + off); off += NEDGES;
    float* sval   = (float*)d_ws + off;      off += NEDGES;
    size_t needed = off * sizeof(float);

    dim3 blk(256);

    if (ws_size >= needed) {
        // ---- CSR build ----
        k_zero_i<<<256, blk, 0, stream>>>(cnt, NNODES);
        k_hist<<<2048, blk, 0, stream>>>(rows, cnt);
        k_bsum<<<NB, blk, 0, stream>>>(cnt, bsum);
        k_scanb<<<1, dim3(1024), 0, stream>>>(bsum, boff, NB);
        k_rowptr<<<NB, blk, 0, stream>>>(cnt, boff, rowptr, cursor);
        k_scatter<<<2048, blk, 0, stream>>>(rows, cols, vals, cursor, scol, sval);

        // ---- 3 gather layers, fused output accumulation ----
        k_spmm_csr<1><<<NNODES / 4, blk, 0, stream>>>(rowptr, scol, sval,
                                                      groups, items, nullptr, x1, out);
        k_spmm_csr<2><<<NNODES / 4, blk, 0, stream>>>(rowptr, scol, sval,
                                                      groups, items, x1, x2, out);
        k_spmm_csr<3><<<NGROUPS / 4, blk, 0, stream>>>(rowptr, scol, sval,
                                                       groups, items, x2, nullptr, out);
    } else {
        // ---- fallback: proven atomic-scatter path ----
        float* xA = x1;
        float* xB = x2;
        k_concat<<<2048, blk, 0, stream>>>((const float4*)groups, (const float4*)items,
                                           (float4*)xA);
        for (int l = 0; l < 3; ++l) {
            k_zero<<<2048, blk, 0, stream>>>((float4*)xB, NNODES * DIM / 4);
            k_spmm<<<4096, blk, 0, stream>>>(rows, cols, vals, xA, xB);
            k_accum<<<512, blk, 0, stream>>>((const float4*)xB, (float4*)out, l == 0);
            float* t = xA; xA = xB; xB = t;
        }
        k_final<<<512, blk, 0, stream>>>((const float4*)groups, (float4*)out);
    }
}

// Round 6
// 625.203 us; speedup vs baseline: 2.6220x; 1.1178x over previous
//
#include <hip/hip_runtime.h>

#define NGROUPS 50000
#define NITEMS  100000
#define NNODES  150000
#define NEDGES  2400000
#define DIM     64

// ============================ CSR-gather path ==============================

__global__ __launch_bounds__(256) void k_zero_i(int* __restrict__ p, int n) {
    int i = blockIdx.x * blockDim.x + threadIdx.x;
    int s = gridDim.x * blockDim.x;
    for (; i < n; i += s) p[i] = 0;
}

__global__ __launch_bounds__(256) void k_hist(const int* __restrict__ rows,
                                              int* __restrict__ cnt) {
    int i = blockIdx.x * blockDim.x + threadIdx.x;
    int s = gridDim.x * blockDim.x;
    for (; i < NEDGES; i += s) atomicAdd(&cnt[rows[i]], 1);
}

__global__ __launch_bounds__(256) void k_bsum(const int* __restrict__ cnt,
                                              int* __restrict__ bsum) {
    __shared__ int s[256];
    int t = threadIdx.x;
    int i = blockIdx.x * 256 + t;
    s[t] = (i < NNODES) ? cnt[i] : 0;
    __syncthreads();
    for (int off = 128; off > 0; off >>= 1) {
        if (t < off) s[t] += s[t + off];
        __syncthreads();
    }
    if (t == 0) bsum[blockIdx.x] = s[0];
}

__global__ __launch_bounds__(1024) void k_scanb(const int* __restrict__ bsum,
                                                int* __restrict__ boff, int nb) {
    __shared__ int s[1024];
    int t = threadIdx.x;
    int v = (t < nb) ? bsum[t] : 0;
    s[t] = v;
    __syncthreads();
    for (int off = 1; off < 1024; off <<= 1) {
        int u = (t >= off) ? s[t - off] : 0;
        __syncthreads();
        s[t] += u;
        __syncthreads();
    }
    if (t < nb) boff[t] = s[t] - v;   // exclusive
}

__global__ __launch_bounds__(256) void k_rowptr(const int* __restrict__ cnt,
                                                const int* __restrict__ boff,
                                                int* __restrict__ rowptr,
                                                int* __restrict__ cursor) {
    __shared__ int s[256];
    int t = threadIdx.x;
    int i = blockIdx.x * 256 + t;
    int c = (i < NNODES) ? cnt[i] : 0;
    s[t] = c;
    __syncthreads();
    for (int off = 1; off < 256; off <<= 1) {
        int u = (t >= off) ? s[t - off] : 0;
        __syncthreads();
        s[t] += u;
        __syncthreads();
    }
    int base = boff[blockIdx.x];
    int excl = base + s[t] - c;
    if (i < NNODES) {
        rowptr[i] = excl;
        cursor[i] = excl;
        if (i == NNODES - 1) rowptr[NNODES] = excl + c;   // == NEDGES
    }
}

// permute (col,val) into row-sorted order — ONE int2 store per edge
// (two 4B stores to two arrays dirtied two cache lines; int2 dirties one)
__global__ __launch_bounds__(256) void k_scatter(const int* __restrict__ rows,
                                                 const int* __restrict__ cols,
                                                 const float* __restrict__ vals,
                                                 int* __restrict__ cursor,
                                                 int2* __restrict__ scv) {
    int i = blockIdx.x * blockDim.x + threadIdx.x;
    int s = gridDim.x * blockDim.x;
    for (; i < NEDGES; i += s) {
        int r = rows[i];
        int pos = atomicAdd(&cursor[r], 1);
        scv[pos] = make_int2(cols[i], __float_as_int(vals[i]));
    }
}

// ---- gather SpMM: one wave per row; 4 lane-quarters each own an edge,
// 16 lanes * float4 = 256B coalesced row gather; 4 gathers in flight/wave.
// LAYER 1: src = groups|items, y = x1, out[r] = acc (r<NGROUPS)
// LAYER 2: src = x1, y = x2, out[r] += acc
// LAYER 3: rows [0,NGROUPS) only; src = x2; out[r] = (out[r]+groups[r]+acc)*.25
template <int LAYER>
__global__ __launch_bounds__(256) void k_spmm_csr(const int* __restrict__ rowptr,
                                                  const int2* __restrict__ scv,
                                                  const float* __restrict__ groups,
                                                  const float* __restrict__ items,
                                                  const float* __restrict__ xsrc,
                                                  float* __restrict__ y,
                                                  float* __restrict__ out) {
    int r    = blockIdx.x * 4 + (threadIdx.x >> 6);
    int lane = threadIdx.x & 63;
    int q    = lane >> 4;      // quarter 0..3 — which edge of a group of 4
    int sl   = lane & 15;      // 0..15 — float4 slot within the row
    int beg = rowptr[r], end = rowptr[r + 1];

    float4 acc = make_float4(0.f, 0.f, 0.f, 0.f);
    for (int j = beg + q; j < end; j += 4) {
        int2  cv = scv[j];
        int   c  = cv.x;
        float v  = __int_as_float(cv.y);
        const float4* src;
        if (LAYER == 1) {
            src = (c < NGROUPS) ? (const float4*)(groups + (size_t)c * DIM)
                                : (const float4*)(items + (size_t)(c - NGROUPS) * DIM);
        } else {
            src = (const float4*)(xsrc + (size_t)c * DIM);
        }
        float4 g = src[sl];
        acc.x = fmaf(v, g.x, acc.x);
        acc.y = fmaf(v, g.y, acc.y);
        acc.z = fmaf(v, g.z, acc.z);
        acc.w = fmaf(v, g.w, acc.w);
    }
    // combine the 4 quarters: lanes end up all holding the full row sum
    acc.x += __shfl_xor(acc.x, 16, 64);
    acc.y += __shfl_xor(acc.y, 16, 64);
    acc.z += __shfl_xor(acc.z, 16, 64);
    acc.w += __shfl_xor(acc.w, 16, 64);
    acc.x += __shfl_xor(acc.x, 32, 64);
    acc.y += __shfl_xor(acc.y, 32, 64);
    acc.z += __shfl_xor(acc.z, 32, 64);
    acc.w += __shfl_xor(acc.w, 32, 64);

    if (lane < 16) {
        size_t o = (size_t)r * 16 + sl;     // float4 index
        if (LAYER == 1) {
            ((float4*)y)[o] = acc;
            if (r < NGROUPS) ((float4*)out)[o] = acc;
        } else if (LAYER == 2) {
            ((float4*)y)[o] = acc;
            if (r < NGROUPS) {
                float4 a = ((float4*)out)[o];
                a.x += acc.x; a.y += acc.y; a.z += acc.z; a.w += acc.w;
                ((float4*)out)[o] = a;
            }
        } else {
            float4 a = ((float4*)out)[o];
            float4 g = ((const float4*)groups)[o];
            a.x = (a.x + g.x + acc.x) * 0.25f;
            a.y = (a.y + g.y + acc.y) * 0.25f;
            a.z = (a.z + g.z + acc.z) * 0.25f;
            a.w = (a.w + g.w + acc.w) * 0.25f;
            ((float4*)out)[o] = a;
        }
    }
}

// ====================== fallback path (atomic scatter) ======================

__global__ __launch_bounds__(256) void k_zero(float4* __restrict__ p, int n4) {
    int i = blockIdx.x * blockDim.x + threadIdx.x;
    int s = gridDim.x * blockDim.x;
    float4 z = make_float4(0.f, 0.f, 0.f, 0.f);
    for (; i < n4; i += s) p[i] = z;
}

__global__ __launch_bounds__(256) void k_concat(const float4* __restrict__ g,
                                                const float4* __restrict__ it,
                                                float4* __restrict__ x) {
    const int n1 = NGROUPS * DIM / 4;
    const int n  = NNODES * DIM / 4;
    int i = blockIdx.x * blockDim.x + threadIdx.x;
    int s = gridDim.x * blockDim.x;
    for (; i < n; i += s) x[i] = (i < n1) ? g[i] : it[i - n1];
}

__global__ __launch_bounds__(256) void k_spmm(const int*   __restrict__ rows,
                                              const int*   __restrict__ cols,
                                              const float* __restrict__ vals,
                                              const float* __restrict__ x,
                                              float*       __restrict__ y) {
    int wid  = (blockIdx.x * blockDim.x + threadIdx.x) >> 6;
    int lane = threadIdx.x & 63;
    int nw   = (gridDim.x * blockDim.x) >> 6;
    for (int e = wid; e < NEDGES; e += nw) {
        int   r = rows[e];
        int   c = cols[e];
        float v = vals[e];
        unsafeAtomicAdd(&y[r * DIM + lane], v * x[c * DIM + lane]);
    }
}

__global__ __launch_bounds__(256) void k_accum(const float4* __restrict__ src,
                                               float4* __restrict__ dst, int first) {
    const int n = NGROUPS * DIM / 4;
    int i = blockIdx.x * blockDim.x + threadIdx.x;
    int s = gridDim.x * blockDim.x;
    if (first) { for (; i < n; i += s) dst[i] = src[i]; }
    else {
        for (; i < n; i += s) {
            float4 a = dst[i], b = src[i];
            a.x += b.x; a.y += b.y; a.z += b.z; a.w += b.w;
            dst[i] = a;
        }
    }
}

__global__ __launch_bounds__(256) void k_final(const float4* __restrict__ g,
                                               float4* __restrict__ out) {
    const int n = NGROUPS * DIM / 4;
    int i = blockIdx.x * blockDim.x + threadIdx.x;
    int s = gridDim.x * blockDim.x;
    for (; i < n; i += s) {
        float4 a = out[i], b = g[i];
        out[i] = make_float4((a.x + b.x) * 0.25f, (a.y + b.y) * 0.25f,
                             (a.z + b.z) * 0.25f, (a.w + b.w) * 0.25f);
    }
}

// ===========================================================================

extern "C" void kernel_launch(void* const* d_in, const int* in_sizes, int n_in,
                              void* d_out, int out_size, void* d_ws, size_t ws_size,
                              hipStream_t stream) {
    const float* groups = (const float*)d_in[0];
    const float* items  = (const float*)d_in[1];
    const float* vals   = (const float*)d_in[2];
    const int*   rows   = (const int*)d_in[3];
    const int*   cols   = (const int*)d_in[4];
    float* out = (float*)d_out;

    const int NB = (NNODES + 255) / 256;              // 586 blocks

    // ws layout (float units)
    size_t off = 0;
    float* x1     = (float*)d_ws;               off += (size_t)NNODES * DIM;
    float* x2     = (float*)d_ws + off;         off += (size_t)NNODES * DIM;
    int*   cnt    = (int*)((float*)d_ws + off); off += NNODES;
    int*   rowptr = (int*)((float*)d_ws + off); off += NNODES + 4;
    int*   cursor = (int*)((float*)d_ws + off); off += NNODES;
    int*   bsum   = (int*)((float*)d_ws + off); off += 1024;
    int*   boff   = (int*)((float*)d_ws + off); off += 1024;
    int2*  scv    = (int2*)((float*)d_ws + off); off += (size_t)NEDGES * 2; // 8B-aligned (even float off)
    size_t needed = off * sizeof(float);

    dim3 blk(256);

    if (ws_size >= needed) {
        // ---- CSR build ----
        k_zero_i<<<256, blk, 0, stream>>>(cnt, NNODES);
        k_hist<<<2048, blk, 0, stream>>>(rows, cnt);
        k_bsum<<<NB, blk, 0, stream>>>(cnt, bsum);
        k_scanb<<<1, dim3(1024), 0, stream>>>(bsum, boff, NB);
        k_rowptr<<<NB, blk, 0, stream>>>(cnt, boff, rowptr, cursor);
        k_scatter<<<2048, blk, 0, stream>>>(rows, cols, vals, cursor, scv);

        // ---- 3 gather layers, fused output accumulation ----
        k_spmm_csr<1><<<NNODES / 4, blk, 0, stream>>>(rowptr, scv,
                                                      groups, items, nullptr, x1, out);
        k_spmm_csr<2><<<NNODES / 4, blk, 0, stream>>>(rowptr, scv,
                                                      groups, items, x1, x2, out);
        k_spmm_csr<3><<<NGROUPS / 4, blk, 0, stream>>>(rowptr, scv,
                                                       groups, items, x2, nullptr, out);
    } else {
        // ---- fallback: proven atomic-scatter path ----
        float* xA = x1;
        float* xB = x2;
        k_concat<<<2048, blk, 0, stream>>>((const float4*)groups, (const float4*)items,
                                           (float4*)xA);
        for (int l = 0; l < 3; ++l) {
            k_zero<<<2048, blk, 0, stream>>>((float4*)xB, NNODES * DIM / 4);
            k_spmm<<<4096, blk, 0, stream>>>(rows, cols, vals, xA, xB);
            k_accum<<<512, blk, 0, stream>>>((const float4*)xB, (float4*)out, l == 0);
            float* t = xA; xA = xB; xB = t;
        }
        k_final<<<512, blk, 0, stream>>>((const float4*)groups, (float4*)out);
    }
}

// Round 7
// 497.460 us; speedup vs baseline: 3.2953x; 1.2568x over previous
//
#include <hip/hip_runtime.h>

#define NGROUPS 50000
#define NITEMS  100000
#define NNODES  150000
#define NEDGES  2400000
#define DIM     64

// ============================ CSR-gather path ==============================

__global__ __launch_bounds__(256) void k_zero_i(int* __restrict__ p, int n) {
    int i = blockIdx.x * blockDim.x + threadIdx.x;
    int s = gridDim.x * blockDim.x;
    for (; i < n; i += s) p[i] = 0;
}

// histogram of row indices; ALSO records each edge's intra-row rank
// (counting-sort trick: the atomicAdd return we used to discard IS the rank,
//  so the later permute needs no atomics at all)
__global__ __launch_bounds__(256) void k_hist(const int* __restrict__ rows,
                                              int* __restrict__ cnt,
                                              int* __restrict__ rank) {
    int i = blockIdx.x * blockDim.x + threadIdx.x;
    int s = gridDim.x * blockDim.x;
    for (; i < NEDGES; i += s) rank[i] = atomicAdd(&cnt[rows[i]], 1);
}

__global__ __launch_bounds__(256) void k_bsum(const int* __restrict__ cnt,
                                              int* __restrict__ bsum) {
    __shared__ int s[256];
    int t = threadIdx.x;
    int i = blockIdx.x * 256 + t;
    s[t] = (i < NNODES) ? cnt[i] : 0;
    __syncthreads();
    for (int off = 128; off > 0; off >>= 1) {
        if (t < off) s[t] += s[t + off];
        __syncthreads();
    }
    if (t == 0) bsum[blockIdx.x] = s[0];
}

__global__ __launch_bounds__(1024) void k_scanb(const int* __restrict__ bsum,
                                                int* __restrict__ boff, int nb) {
    __shared__ int s[1024];
    int t = threadIdx.x;
    int v = (t < nb) ? bsum[t] : 0;
    s[t] = v;
    __syncthreads();
    for (int off = 1; off < 1024; off <<= 1) {
        int u = (t >= off) ? s[t - off] : 0;
        __syncthreads();
        s[t] += u;
        __syncthreads();
    }
    if (t < nb) boff[t] = s[t] - v;   // exclusive
}

__global__ __launch_bounds__(256) void k_rowptr(const int* __restrict__ cnt,
                                                const int* __restrict__ boff,
                                                int* __restrict__ rowptr) {
    __shared__ int s[256];
    int t = threadIdx.x;
    int i = blockIdx.x * 256 + t;
    int c = (i < NNODES) ? cnt[i] : 0;
    s[t] = c;
    __syncthreads();
    for (int off = 1; off < 256; off <<= 1) {
        int u = (t >= off) ? s[t - off] : 0;
        __syncthreads();
        s[t] += u;
        __syncthreads();
    }
    int base = boff[blockIdx.x];
    int excl = base + s[t] - c;
    if (i < NNODES) {
        rowptr[i] = excl;
        if (i == NNODES - 1) rowptr[NNODES] = excl + c;   // == NEDGES
    }
}

// permute (col,val) into row-sorted order — ATOMIC-FREE:
// pos = rowptr[r] + rank[i]; all loads are sequential streams except the
// cached 600KB rowptr gather; the random 8B store is fire-and-forget.
__global__ __launch_bounds__(256) void k_scatter(const int* __restrict__ rows,
                                                 const int* __restrict__ cols,
                                                 const float* __restrict__ vals,
                                                 const int* __restrict__ rank,
                                                 const int* __restrict__ rowptr,
                                                 int2* __restrict__ scv) {
    int i = blockIdx.x * blockDim.x + threadIdx.x;
    int s = gridDim.x * blockDim.x;
    for (; i < NEDGES; i += s) {
        int r   = rows[i];
        int pos = rowptr[r] + rank[i];
        scv[pos] = make_int2(cols[i], __float_as_int(vals[i]));
    }
}

// ---- gather SpMM: one wave per row; 4 lane-quarters each own an edge,
// 16 lanes * float4 = 256B coalesced row gather; 4 gathers in flight/wave.
// LAYER 1: src = groups|items, y = x1, out[r] = acc (r<NGROUPS)
// LAYER 2: src = x1, y = x2, out[r] += acc
// LAYER 3: rows [0,NGROUPS) only; src = x2; out[r] = (out[r]+groups[r]+acc)*.25
template <int LAYER>
__global__ __launch_bounds__(256) void k_spmm_csr(const int* __restrict__ rowptr,
                                                  const int2* __restrict__ scv,
                                                  const float* __restrict__ groups,
                                                  const float* __restrict__ items,
                                                  const float* __restrict__ xsrc,
                                                  float* __restrict__ y,
                                                  float* __restrict__ out) {
    int r    = blockIdx.x * 4 + (threadIdx.x >> 6);
    int lane = threadIdx.x & 63;
    int q    = lane >> 4;      // quarter 0..3 — which edge of a group of 4
    int sl   = lane & 15;      // 0..15 — float4 slot within the row
    int beg = rowptr[r], end = rowptr[r + 1];

    float4 acc = make_float4(0.f, 0.f, 0.f, 0.f);
    for (int j = beg + q; j < end; j += 4) {
        int2  cv = scv[j];
        int   c  = cv.x;
        float v  = __int_as_float(cv.y);
        const float4* src;
        if (LAYER == 1) {
            src = (c < NGROUPS) ? (const float4*)(groups + (size_t)c * DIM)
                                : (const float4*)(items + (size_t)(c - NGROUPS) * DIM);
        } else {
            src = (const float4*)(xsrc + (size_t)c * DIM);
        }
        float4 g = src[sl];
        acc.x = fmaf(v, g.x, acc.x);
        acc.y = fmaf(v, g.y, acc.y);
        acc.z = fmaf(v, g.z, acc.z);
        acc.w = fmaf(v, g.w, acc.w);
    }
    // combine the 4 quarters: all lanes end up holding the full row sum
    acc.x += __shfl_xor(acc.x, 16, 64);
    acc.y += __shfl_xor(acc.y, 16, 64);
    acc.z += __shfl_xor(acc.z, 16, 64);
    acc.w += __shfl_xor(acc.w, 16, 64);
    acc.x += __shfl_xor(acc.x, 32, 64);
    acc.y += __shfl_xor(acc.y, 32, 64);
    acc.z += __shfl_xor(acc.z, 32, 64);
    acc.w += __shfl_xor(acc.w, 32, 64);

    if (lane < 16) {
        size_t o = (size_t)r * 16 + sl;     // float4 index
        if (LAYER == 1) {
            ((float4*)y)[o] = acc;
            if (r < NGROUPS) ((float4*)out)[o] = acc;
        } else if (LAYER == 2) {
            ((float4*)y)[o] = acc;
            if (r < NGROUPS) {
                float4 a = ((float4*)out)[o];
                a.x += acc.x; a.y += acc.y; a.z += acc.z; a.w += acc.w;
                ((float4*)out)[o] = a;
            }
        } else {
            float4 a = ((float4*)out)[o];
            float4 g = ((const float4*)groups)[o];
            a.x = (a.x + g.x + acc.x) * 0.25f;
            a.y = (a.y + g.y + acc.y) * 0.25f;
            a.z = (a.z + g.z + acc.z) * 0.25f;
            a.w = (a.w + g.w + acc.w) * 0.25f;
            ((float4*)out)[o] = a;
        }
    }
}

// ====================== fallback path (atomic scatter) ======================

__global__ __launch_bounds__(256) void k_zero(float4* __restrict__ p, int n4) {
    int i = blockIdx.x * blockDim.x + threadIdx.x;
    int s = gridDim.x * blockDim.x;
    float4 z = make_float4(0.f, 0.f, 0.f, 0.f);
    for (; i < n4; i += s) p[i] = z;
}

__global__ __launch_bounds__(256) void k_concat(const float4* __restrict__ g,
                                                const float4* __restrict__ it,
                                                float4* __restrict__ x) {
    const int n1 = NGROUPS * DIM / 4;
    const int n  = NNODES * DIM / 4;
    int i = blockIdx.x * blockDim.x + threadIdx.x;
    int s = gridDim.x * blockDim.x;
    for (; i < n; i += s) x[i] = (i < n1) ? g[i] : it[i - n1];
}

__global__ __launch_bounds__(256) void k_spmm(const int*   __restrict__ rows,
                                              const int*   __restrict__ cols,
                                              const float* __restrict__ vals,
                                              const float* __restrict__ x,
                                              float*       __restrict__ y) {
    int wid  = (blockIdx.x * blockDim.x + threadIdx.x) >> 6;
    int lane = threadIdx.x & 63;
    int nw   = (gridDim.x * blockDim.x) >> 6;
    for (int e = wid; e < NEDGES; e += nw) {
        int   r = rows[e];
        int   c = cols[e];
        float v = vals[e];
        unsafeAtomicAdd(&y[r * DIM + lane], v * x[c * DIM + lane]);
    }
}

__global__ __launch_bounds__(256) void k_accum(const float4* __restrict__ src,
                                               float4* __restrict__ dst, int first) {
    const int n = NGROUPS * DIM / 4;
    int i = blockIdx.x * blockDim.x + threadIdx.x;
    int s = gridDim.x * blockDim.x;
    if (first) { for (; i < n; i += s) dst[i] = src[i]; }
    else {
        for (; i < n; i += s) {
            float4 a = dst[i], b = src[i];
            a.x += b.x; a.y += b.y; a.z += b.z; a.w += b.w;
            dst[i] = a;
        }
    }
}

__global__ __launch_bounds__(256) void k_final(const float4* __restrict__ g,
                                               float4* __restrict__ out) {
    const int n = NGROUPS * DIM / 4;
    int i = blockIdx.x * blockDim.x + threadIdx.x;
    int s = gridDim.x * blockDim.x;
    for (; i < n; i += s) {
        float4 a = out[i], b = g[i];
        out[i] = make_float4((a.x + b.x) * 0.25f, (a.y + b.y) * 0.25f,
                             (a.z + b.z) * 0.25f, (a.w + b.w) * 0.25f);
    }
}

// ===========================================================================

extern "C" void kernel_launch(void* const* d_in, const int* in_sizes, int n_in,
                              void* d_out, int out_size, void* d_ws, size_t ws_size,
                              hipStream_t stream) {
    const float* groups = (const float*)d_in[0];
    const float* items  = (const float*)d_in[1];
    const float* vals   = (const float*)d_in[2];
    const int*   rows   = (const int*)d_in[3];
    const int*   cols   = (const int*)d_in[4];
    float* out = (float*)d_out;

    const int NB = (NNODES + 255) / 256;              // 586 blocks

    // ws layout (float units)
    size_t off = 0;
    float* x1     = (float*)d_ws;               off += (size_t)NNODES * DIM;
    float* x2     = (float*)d_ws + off;         off += (size_t)NNODES * DIM;
    int*   cnt    = (int*)((float*)d_ws + off); off += NNODES;
    int*   rowptr = (int*)((float*)d_ws + off); off += NNODES + 4;
    int*   bsum   = (int*)((float*)d_ws + off); off += 1024;
    int*   boff   = (int*)((float*)d_ws + off); off += 1024;
    int2*  scv    = (int2*)((float*)d_ws + off); off += (size_t)NEDGES * 2; // 8B-aligned
    size_t needed = off * sizeof(float);

    // rank[] is only live between k_hist and k_scatter; x2 is only written
    // by the layer-2 SpMM (after scatter) — alias rank onto x2, no ws growth.
    int* rank = (int*)x2;

    dim3 blk(256);

    if (ws_size >= needed) {
        // ---- CSR build (atomic-free permute via counting-sort ranks) ----
        k_zero_i<<<256, blk, 0, stream>>>(cnt, NNODES);
        k_hist<<<2048, blk, 0, stream>>>(rows, cnt, rank);
        k_bsum<<<NB, blk, 0, stream>>>(cnt, bsum);
        k_scanb<<<1, dim3(1024), 0, stream>>>(bsum, boff, NB);
        k_rowptr<<<NB, blk, 0, stream>>>(cnt, boff, rowptr);
        k_scatter<<<2048, blk, 0, stream>>>(rows, cols, vals, rank, rowptr, scv);

        // ---- 3 gather layers, fused output accumulation ----
        k_spmm_csr<1><<<NNODES / 4, blk, 0, stream>>>(rowptr, scv,
                                                      groups, items, nullptr, x1, out);
        k_spmm_csr<2><<<NNODES / 4, blk, 0, stream>>>(rowptr, scv,
                                                      groups, items, x1, x2, out);
        k_spmm_csr<3><<<NGROUPS / 4, blk, 0, stream>>>(rowptr, scv,
                                                       groups, items, x2, nullptr, out);
    } else {
        // ---- fallback: proven atomic-scatter path ----
        float* xA = x1;
        float* xB = x2;
        k_concat<<<2048, blk, 0, stream>>>((const float4*)groups, (const float4*)items,
                                           (float4*)xA);
        for (int l = 0; l < 3; ++l) {
            k_zero<<<2048, blk, 0, stream>>>((float4*)xB, NNODES * DIM / 4);
            k_spmm<<<4096, blk, 0, stream>>>(rows, cols, vals, xA, xB);
            k_accum<<<512, blk, 0, stream>>>((const float4*)xB, (float4*)out, l == 0);
            float* t = xA; xA = xB; xB = t;
        }
        k_final<<<512, blk, 0, stream>>>((const float4*)groups, (float4*)out);
    }
}

// Round 8
// 488.707 us; speedup vs baseline: 3.3543x; 1.0179x over previous
//
#include <hip/hip_runtime.h>

#define NGROUPS 50000
#define NITEMS  100000
#define NNODES  150000
#define NEDGES  2400000
#define DIM     64

// round-to-nearest f32 -> bf16 (as raw ushort)
__device__ __forceinline__ ushort f2bf(float f) {
    unsigned u = __float_as_uint(f);
    u += 0x7FFF + ((u >> 16) & 1);
    return (ushort)(u >> 16);
}
__device__ __forceinline__ float bf2f(ushort h) {
    return __uint_as_float((unsigned)h << 16);
}

// ============================ CSR-gather path ==============================

__global__ __launch_bounds__(256) void k_zero_i(int* __restrict__ p, int n) {
    int i = blockIdx.x * blockDim.x + threadIdx.x;
    int s = gridDim.x * blockDim.x;
    for (; i < n; i += s) p[i] = 0;
}

// all_emb (f32 groups||items) -> bf16 table x0b
__global__ __launch_bounds__(256) void k_tobf16(const float4* __restrict__ g,
                                                const float4* __restrict__ it,
                                                ushort4* __restrict__ xb) {
    const int n1 = NGROUPS * DIM / 4;
    const int n  = NNODES * DIM / 4;
    int i = blockIdx.x * blockDim.x + threadIdx.x;
    int s = gridDim.x * blockDim.x;
    for (; i < n; i += s) {
        float4 v = (i < n1) ? g[i] : it[i - n1];
        ushort4 h;
        h.x = f2bf(v.x); h.y = f2bf(v.y); h.z = f2bf(v.z); h.w = f2bf(v.w);
        xb[i] = h;
    }
}

// histogram of row indices + intra-row rank (counting-sort trick),
// 4 edges/thread: int4 loads, 4 independent atomics in flight.
__global__ __launch_bounds__(256) void k_hist(const int4* __restrict__ rows4,
                                              int* __restrict__ cnt,
                                              int4* __restrict__ rank4) {
    const int n4 = NEDGES / 4;
    int i = blockIdx.x * blockDim.x + threadIdx.x;
    int s = gridDim.x * blockDim.x;
    for (; i < n4; i += s) {
        int4 r = rows4[i];
        int4 k;
        k.x = atomicAdd(&cnt[r.x], 1);
        k.y = atomicAdd(&cnt[r.y], 1);
        k.z = atomicAdd(&cnt[r.z], 1);
        k.w = atomicAdd(&cnt[r.w], 1);
        rank4[i] = k;
    }
}

__global__ __launch_bounds__(256) void k_bsum(const int* __restrict__ cnt,
                                              int* __restrict__ bsum) {
    __shared__ int s[256];
    int t = threadIdx.x;
    int i = blockIdx.x * 256 + t;
    s[t] = (i < NNODES) ? cnt[i] : 0;
    __syncthreads();
    for (int off = 128; off > 0; off >>= 1) {
        if (t < off) s[t] += s[t + off];
        __syncthreads();
    }
    if (t == 0) bsum[blockIdx.x] = s[0];
}

__global__ __launch_bounds__(1024) void k_scanb(const int* __restrict__ bsum,
                                                int* __restrict__ boff, int nb) {
    __shared__ int s[1024];
    int t = threadIdx.x;
    int v = (t < nb) ? bsum[t] : 0;
    s[t] = v;
    __syncthreads();
    for (int off = 1; off < 1024; off <<= 1) {
        int u = (t >= off) ? s[t - off] : 0;
        __syncthreads();
        s[t] += u;
        __syncthreads();
    }
    if (t < nb) boff[t] = s[t] - v;   // exclusive
}

__global__ __launch_bounds__(256) void k_rowptr(const int* __restrict__ cnt,
                                                const int* __restrict__ boff,
                                                int* __restrict__ rowptr) {
    __shared__ int s[256];
    int t = threadIdx.x;
    int i = blockIdx.x * 256 + t;
    int c = (i < NNODES) ? cnt[i] : 0;
    s[t] = c;
    __syncthreads();
    for (int off = 1; off < 256; off <<= 1) {
        int u = (t >= off) ? s[t - off] : 0;
        __syncthreads();
        s[t] += u;
        __syncthreads();
    }
    int base = boff[blockIdx.x];
    int excl = base + s[t] - c;
    if (i < NNODES) {
        rowptr[i] = excl;
        if (i == NNODES - 1) rowptr[NNODES] = excl + c;   // == NEDGES
    }
}

// atomic-free permute: pos = rowptr[r] + rank[i]; 4 edges/thread.
__global__ __launch_bounds__(256) void k_scatter(const int4* __restrict__ rows4,
                                                 const int4* __restrict__ cols4,
                                                 const float4* __restrict__ vals4,
                                                 const int4* __restrict__ rank4,
                                                 const int* __restrict__ rowptr,
                                                 int2* __restrict__ scv) {
    const int n4 = NEDGES / 4;
    int i = blockIdx.x * blockDim.x + threadIdx.x;
    int s = gridDim.x * blockDim.x;
    for (; i < n4; i += s) {
        int4   r = rows4[i];
        int4   c = cols4[i];
        float4 v = vals4[i];
        int4   k = rank4[i];
        scv[rowptr[r.x] + k.x] = make_int2(c.x, __float_as_int(v.x));
        scv[rowptr[r.y] + k.y] = make_int2(c.y, __float_as_int(v.y));
        scv[rowptr[r.z] + k.z] = make_int2(c.z, __float_as_int(v.z));
        scv[rowptr[r.w] + k.w] = make_int2(c.w, __float_as_int(v.w));
    }
}

// ---- gather SpMM over bf16 x-table: one wave per row; 4 lane-quarters each
// own an edge; 16 lanes * ushort4 = 128B = ONE cache line per edge gather.
// LAYER 1: gather x0b, write y=x1b, out[r] = acc (f32, r<NGROUPS)
// LAYER 2: gather x1b, write y=x2b, out[r] += acc
// LAYER 3: rows [0,NGROUPS) only; gather x2b; out = (out+groups+acc)*0.25
template <int LAYER>
__global__ __launch_bounds__(256) void k_spmm_csr(const int* __restrict__ rowptr,
                                                  const int2* __restrict__ scv,
                                                  const ushort* __restrict__ xsrc,
                                                  const float4* __restrict__ groups4,
                                                  ushort* __restrict__ y,
                                                  float4* __restrict__ out4) {
    int r    = blockIdx.x * 4 + (threadIdx.x >> 6);
    int lane = threadIdx.x & 63;
    int q    = lane >> 4;      // quarter 0..3 — which edge of a group of 4
    int sl   = lane & 15;      // 0..15 — ushort4 slot within the row
    int beg = rowptr[r], end = rowptr[r + 1];

    float4 acc = make_float4(0.f, 0.f, 0.f, 0.f);
    for (int j = beg + q; j < end; j += 4) {
        int2  cv = scv[j];
        int   c  = cv.x;
        float v  = __int_as_float(cv.y);
        ushort4 h = ((const ushort4*)(xsrc + (size_t)c * DIM))[sl];
        acc.x = fmaf(v, bf2f(h.x), acc.x);
        acc.y = fmaf(v, bf2f(h.y), acc.y);
        acc.z = fmaf(v, bf2f(h.z), acc.z);
        acc.w = fmaf(v, bf2f(h.w), acc.w);
    }
    // combine the 4 quarters: all lanes end up holding the full row sum
    acc.x += __shfl_xor(acc.x, 16, 64);
    acc.y += __shfl_xor(acc.y, 16, 64);
    acc.z += __shfl_xor(acc.z, 16, 64);
    acc.w += __shfl_xor(acc.w, 16, 64);
    acc.x += __shfl_xor(acc.x, 32, 64);
    acc.y += __shfl_xor(acc.y, 32, 64);
    acc.z += __shfl_xor(acc.z, 32, 64);
    acc.w += __shfl_xor(acc.w, 32, 64);

    if (lane < 16) {
        size_t o = (size_t)r * 16 + sl;     // float4 / ushort4 row slot
        if (LAYER != 3) {
            ushort4 h;
            h.x = f2bf(acc.x); h.y = f2bf(acc.y);
            h.z = f2bf(acc.z); h.w = f2bf(acc.w);
            ((ushort4*)(y + (size_t)r * DIM))[sl] = h;
        }
        if (LAYER == 1) {
            if (r < NGROUPS) out4[o] = acc;
        } else if (LAYER == 2) {
            if (r < NGROUPS) {
                float4 a = out4[o];
                a.x += acc.x; a.y += acc.y; a.z += acc.z; a.w += acc.w;
                out4[o] = a;
            }
        } else {
            float4 a = out4[o];
            float4 g = groups4[o];
            a.x = (a.x + g.x + acc.x) * 0.25f;
            a.y = (a.y + g.y + acc.y) * 0.25f;
            a.z = (a.z + g.z + acc.z) * 0.25f;
            a.w = (a.w + g.w + acc.w) * 0.25f;
            out4[o] = a;
        }
    }
}

// ====================== fallback path (atomic scatter) ======================

__global__ __launch_bounds__(256) void k_zero(float4* __restrict__ p, int n4) {
    int i = blockIdx.x * blockDim.x + threadIdx.x;
    int s = gridDim.x * blockDim.x;
    float4 z = make_float4(0.f, 0.f, 0.f, 0.f);
    for (; i < n4; i += s) p[i] = z;
}

__global__ __launch_bounds__(256) void k_concat(const float4* __restrict__ g,
                                                const float4* __restrict__ it,
                                                float4* __restrict__ x) {
    const int n1 = NGROUPS * DIM / 4;
    const int n  = NNODES * DIM / 4;
    int i = blockIdx.x * blockDim.x + threadIdx.x;
    int s = gridDim.x * blockDim.x;
    for (; i < n; i += s) x[i] = (i < n1) ? g[i] : it[i - n1];
}

__global__ __launch_bounds__(256) void k_spmm(const int*   __restrict__ rows,
                                              const int*   __restrict__ cols,
                                              const float* __restrict__ vals,
                                              const float* __restrict__ x,
                                              float*       __restrict__ y) {
    int wid  = (blockIdx.x * blockDim.x + threadIdx.x) >> 6;
    int lane = threadIdx.x & 63;
    int nw   = (gridDim.x * blockDim.x) >> 6;
    for (int e = wid; e < NEDGES; e += nw) {
        int   r = rows[e];
        int   c = cols[e];
        float v = vals[e];
        unsafeAtomicAdd(&y[r * DIM + lane], v * x[c * DIM + lane]);
    }
}

__global__ __launch_bounds__(256) void k_accum(const float4* __restrict__ src,
                                               float4* __restrict__ dst, int first) {
    const int n = NGROUPS * DIM / 4;
    int i = blockIdx.x * blockDim.x + threadIdx.x;
    int s = gridDim.x * blockDim.x;
    if (first) { for (; i < n; i += s) dst[i] = src[i]; }
    else {
        for (; i < n; i += s) {
            float4 a = dst[i], b = src[i];
            a.x += b.x; a.y += b.y; a.z += b.z; a.w += b.w;
            dst[i] = a;
        }
    }
}

__global__ __launch_bounds__(256) void k_final(const float4* __restrict__ g,
                                               float4* __restrict__ out) {
    const int n = NGROUPS * DIM / 4;
    int i = blockIdx.x * blockDim.x + threadIdx.x;
    int s = gridDim.x * blockDim.x;
    for (; i < n; i += s) {
        float4 a = out[i], b = g[i];
        out[i] = make_float4((a.x + b.x) * 0.25f, (a.y + b.y) * 0.25f,
                             (a.z + b.z) * 0.25f, (a.w + b.w) * 0.25f);
    }
}

// ===========================================================================

extern "C" void kernel_launch(void* const* d_in, const int* in_sizes, int n_in,
                              void* d_out, int out_size, void* d_ws, size_t ws_size,
                              hipStream_t stream) {
    const float* groups = (const float*)d_in[0];
    const float* items  = (const float*)d_in[1];
    const float* vals   = (const float*)d_in[2];
    const int*   rows   = (const int*)d_in[3];
    const int*   cols   = (const int*)d_in[4];
    float* out = (float*)d_out;

    const int NB = (NNODES + 255) / 256;              // 586 blocks

    // ws layout (float units) — regions kept f32-sized so the fallback path
    // (f32 x-buffers) fits the same layout; bf16 tables use the low half.
    size_t off = 0;
    float* x1     = (float*)d_ws;               off += (size_t)NNODES * DIM;
    float* x2     = (float*)d_ws + off;         off += (size_t)NNODES * DIM;
    int*   cnt    = (int*)((float*)d_ws + off); off += NNODES;
    int*   rowptr = (int*)((float*)d_ws + off); off += NNODES + 4;
    int*   bsum   = (int*)((float*)d_ws + off); off += 1024;
    int*   boff   = (int*)((float*)d_ws + off); off += 1024;
    int2*  scv    = (int2*)((float*)d_ws + off); off += (size_t)NEDGES * 2; // 8B-aligned
    float* x0     = (float*)d_ws + off;         off += (size_t)NNODES * DIM / 2; // bf16 table
    size_t needed = off * sizeof(float);

    // bf16 tables: x0b in its own region; x1b/x2b in the (oversized) f32 regions
    ushort* x0b = (ushort*)x0;
    ushort* x1b = (ushort*)x1;
    ushort* x2b = (ushort*)x2;
    // rank[] lives only between k_hist and k_scatter; x2 region is written
    // only by the layer-2 SpMM (after scatter) — alias, no ws growth.
    int* rank = (int*)x2;

    dim3 blk(256);

    if (ws_size >= needed) {
        // ---- bf16 x0 table + CSR build (atomic-free permute) ----
        k_tobf16<<<1024, blk, 0, stream>>>((const float4*)groups, (const float4*)items,
                                           (ushort4*)x0b);
        k_zero_i<<<256, blk, 0, stream>>>(cnt, NNODES);
        k_hist<<<1024, blk, 0, stream>>>((const int4*)rows, cnt, (int4*)rank);
        k_bsum<<<NB, blk, 0, stream>>>(cnt, bsum);
        k_scanb<<<1, dim3(1024), 0, stream>>>(bsum, boff, NB);
        k_rowptr<<<NB, blk, 0, stream>>>(cnt, boff, rowptr);
        k_scatter<<<1024, blk, 0, stream>>>((const int4*)rows, (const int4*)cols,
                                            (const float4*)vals, (const int4*)rank,
                                            rowptr, scv);

        // ---- 3 gather layers (bf16 gathers), fused output accumulation ----
        k_spmm_csr<1><<<NNODES / 4, blk, 0, stream>>>(rowptr, scv, x0b,
                                                      (const float4*)groups, x1b,
                                                      (float4*)out);
        k_spmm_csr<2><<<NNODES / 4, blk, 0, stream>>>(rowptr, scv, x1b,
                                                      (const float4*)groups, x2b,
                                                      (float4*)out);
        k_spmm_csr<3><<<NGROUPS / 4, blk, 0, stream>>>(rowptr, scv, x2b,
                                                       (const float4*)groups, nullptr,
                                                       (float4*)out);
    } else {
        // ---- fallback: proven atomic-scatter path (f32) ----
        float* xA = x1;
        float* xB = x2;
        k_concat<<<2048, blk, 0, stream>>>((const float4*)groups, (const float4*)items,
                                           (float4*)xA);
        for (int l = 0; l < 3; ++l) {
            k_zero<<<2048, blk, 0, stream>>>((float4*)xB, NNODES * DIM / 4);
            k_spmm<<<4096, blk, 0, stream>>>(rows, cols, vals, xA, xB);
            k_accum<<<512, blk, 0, stream>>>((const float4*)xB, (float4*)out, l == 0);
            float* t = xA; xA = xB; xB = t;
        }
        k_final<<<512, blk, 0, stream>>>((const float4*)groups, (float4*)out);
    }
}

// Round 10
// 481.093 us; speedup vs baseline: 3.4074x; 1.0158x over previous
//
#include <hip/hip_runtime.h>

#define NGROUPS 50000
#define NITEMS  100000
#define NNODES  150000
#define NEDGES  2400000
#define DIM     64

// round-to-nearest f32 -> bf16 (as raw ushort)
__device__ __forceinline__ ushort f2bf(float f) {
    unsigned u = __float_as_uint(f);
    u += 0x7FFF + ((u >> 16) & 1);
    return (ushort)(u >> 16);
}
__device__ __forceinline__ float bf2f(ushort h) {
    return __uint_as_float((unsigned)h << 16);
}

// ============================ CSR-gather path ==============================

// FUSED: (a) f32 groups||items -> bf16 table x0b (streaming prologue),
//        (b) row histogram + intra-row rank (counting-sort trick).
// The streaming phase overlaps/staggers the atomic phase across waves.
__global__ __launch_bounds__(256) void k_conv_hist(const float4* __restrict__ g,
                                                   const float4* __restrict__ it,
                                                   ushort4* __restrict__ xb,
                                                   const int4* __restrict__ rows4,
                                                   int* __restrict__ cnt,
                                                   int4* __restrict__ rank4) {
    int tid = blockIdx.x * blockDim.x + threadIdx.x;
    int s   = gridDim.x * blockDim.x;

    const int n1 = NGROUPS * DIM / 4;
    const int nc = NNODES * DIM / 4;
    for (int i = tid; i < nc; i += s) {
        float4 v = (i < n1) ? g[i] : it[i - n1];
        ushort4 h;
        h.x = f2bf(v.x); h.y = f2bf(v.y); h.z = f2bf(v.z); h.w = f2bf(v.w);
        xb[i] = h;
    }

    const int n4 = NEDGES / 4;
    for (int i = tid; i < n4; i += s) {
        int4 r = rows4[i];
        int4 k;
        k.x = atomicAdd(&cnt[r.x], 1);
        k.y = atomicAdd(&cnt[r.y], 1);
        k.z = atomicAdd(&cnt[r.z], 1);
        k.w = atomicAdd(&cnt[r.w], 1);
        rank4[i] = k;
    }
}

__global__ __launch_bounds__(256) void k_bsum(const int* __restrict__ cnt,
                                              int* __restrict__ bsum) {
    __shared__ int s[256];
    int t = threadIdx.x;
    int i = blockIdx.x * 256 + t;
    s[t] = (i < NNODES) ? cnt[i] : 0;
    __syncthreads();
    for (int off = 128; off > 0; off >>= 1) {
        if (t < off) s[t] += s[t + off];
        __syncthreads();
    }
    if (t == 0) bsum[blockIdx.x] = s[0];
}

__global__ __launch_bounds__(1024) void k_scanb(const int* __restrict__ bsum,
                                                int* __restrict__ boff, int nb) {
    __shared__ int s[1024];
    int t = threadIdx.x;
    int v = (t < nb) ? bsum[t] : 0;
    s[t] = v;
    __syncthreads();
    for (int off = 1; off < 1024; off <<= 1) {
        int u = (t >= off) ? s[t - off] : 0;
        __syncthreads();
        s[t] += u;
        __syncthreads();
    }
    if (t < nb) boff[t] = s[t] - v;   // exclusive
}

__global__ __launch_bounds__(256) void k_rowptr(const int* __restrict__ cnt,
                                                const int* __restrict__ boff,
                                                int* __restrict__ rowptr) {
    __shared__ int s[256];
    int t = threadIdx.x;
    int i = blockIdx.x * 256 + t;
    int c = (i < NNODES) ? cnt[i] : 0;
    s[t] = c;
    __syncthreads();
    for (int off = 1; off < 256; off <<= 1) {
        int u = (t >= off) ? s[t - off] : 0;
        __syncthreads();
        s[t] += u;
        __syncthreads();
    }
    int base = boff[blockIdx.x];
    int excl = base + s[t] - c;
    if (i < NNODES) {
        rowptr[i] = excl;
        if (i == NNODES - 1) rowptr[NNODES] = excl + c;   // == NEDGES
    }
}

// atomic-free permute: pos = rowptr[r] + rank[i]; 4 edges/thread.
__global__ __launch_bounds__(256) void k_scatter(const int4* __restrict__ rows4,
                                                 const int4* __restrict__ cols4,
                                                 const float4* __restrict__ vals4,
                                                 const int4* __restrict__ rank4,
                                                 const int* __restrict__ rowptr,
                                                 int2* __restrict__ scv) {
    const int n4 = NEDGES / 4;
    int i = blockIdx.x * blockDim.x + threadIdx.x;
    int s = gridDim.x * blockDim.x;
    for (; i < n4; i += s) {
        int4   r = rows4[i];
        int4   c = cols4[i];
        float4 v = vals4[i];
        int4   k = rank4[i];
        scv[rowptr[r.x] + k.x] = make_int2(c.x, __float_as_int(v.x));
        scv[rowptr[r.y] + k.y] = make_int2(c.y, __float_as_int(v.y));
        scv[rowptr[r.z] + k.z] = make_int2(c.z, __float_as_int(v.z));
        scv[rowptr[r.w] + k.w] = make_int2(c.w, __float_as_int(v.w));
    }
}

// ---- gather SpMM over bf16 x-table: one wave per row; 4 lane-quarters each
// own an edge; 16 lanes * ushort4 = 128B = ONE cache line per edge gather.
// LAYER 1: gather x0b, write y=x1b, out[r] = acc (f32, r<NGROUPS)
// LAYER 2: gather x1b, write y=x2b, out[r] += acc
// LAYER 3: rows [0,NGROUPS) only; gather x2b; out = (out+groups+acc)*0.25
template <int LAYER>
__global__ __launch_bounds__(256) void k_spmm_csr(const int* __restrict__ rowptr,
                                                  const int2* __restrict__ scv,
                                                  const ushort* __restrict__ xsrc,
                                                  const float4* __restrict__ groups4,
                                                  ushort* __restrict__ y,
                                                  float4* __restrict__ out4) {
    int r    = blockIdx.x * 4 + (threadIdx.x >> 6);
    int lane = threadIdx.x & 63;
    int q    = lane >> 4;      // quarter 0..3 — which edge of a group of 4
    int sl   = lane & 15;      // 0..15 — ushort4 slot within the row
    int beg = rowptr[r], end = rowptr[r + 1];

    float4 acc = make_float4(0.f, 0.f, 0.f, 0.f);
    for (int j = beg + q; j < end; j += 4) {
        int2  cv = scv[j];
        int   c  = cv.x;
        float v  = __int_as_float(cv.y);
        ushort4 h = ((const ushort4*)(xsrc + (size_t)c * DIM))[sl];
        acc.x = fmaf(v, bf2f(h.x), acc.x);
        acc.y = fmaf(v, bf2f(h.y), acc.y);
        acc.z = fmaf(v, bf2f(h.z), acc.z);
        acc.w = fmaf(v, bf2f(h.w), acc.w);
    }
    // combine the 4 quarters: all lanes end up holding the full row sum
    acc.x += __shfl_xor(acc.x, 16, 64);
    acc.y += __shfl_xor(acc.y, 16, 64);
    acc.z += __shfl_xor(acc.z, 16, 64);
    acc.w += __shfl_xor(acc.w, 16, 64);
    acc.x += __shfl_xor(acc.x, 32, 64);
    acc.y += __shfl_xor(acc.y, 32, 64);
    acc.z += __shfl_xor(acc.z, 32, 64);
    acc.w += __shfl_xor(acc.w, 32, 64);

    if (lane < 16) {
        size_t o = (size_t)r * 16 + sl;     // float4 / ushort4 row slot
        if (LAYER != 3) {
            ushort4 h;
            h.x = f2bf(acc.x); h.y = f2bf(acc.y);
            h.z = f2bf(acc.z); h.w = f2bf(acc.w);
            ((ushort4*)(y + (size_t)r * DIM))[sl] = h;
        }
        if (LAYER == 1) {
            if (r < NGROUPS) out4[o] = acc;
        } else if (LAYER == 2) {
            if (r < NGROUPS) {
                float4 a = out4[o];
                a.x += acc.x; a.y += acc.y; a.z += acc.z; a.w += acc.w;
                out4[o] = a;
            }
        } else {
            float4 a = out4[o];
            float4 g = groups4[o];
            a.x = (a.x + g.x + acc.x) * 0.25f;
            a.y = (a.y + g.y + acc.y) * 0.25f;
            a.z = (a.z + g.z + acc.z) * 0.25f;
            a.w = (a.w + g.w + acc.w) * 0.25f;
            out4[o] = a;
        }
    }
}

// ====================== fallback path (atomic scatter) ======================

__global__ __launch_bounds__(256) void k_zero(float4* __restrict__ p, int n4) {
    int i = blockIdx.x * blockDim.x + threadIdx.x;
    int s = gridDim.x * blockDim.x;
    float4 z = make_float4(0.f, 0.f, 0.f, 0.f);
    for (; i < n4; i += s) p[i] = z;
}

__global__ __launch_bounds__(256) void k_concat(const float4* __restrict__ g,
                                                const float4* __restrict__ it,
                                                float4* __restrict__ x) {
    const int n1 = NGROUPS * DIM / 4;
    const int n  = NNODES * DIM / 4;
    int i = blockIdx.x * blockDim.x + threadIdx.x;
    int s = gridDim.x * blockDim.x;
    for (; i < n; i += s) x[i] = (i < n1) ? g[i] : it[i - n1];
}

__global__ __launch_bounds__(256) void k_spmm(const int*   __restrict__ rows,
                                              const int*   __restrict__ cols,
                                              const float* __restrict__ vals,
                                              const float* __restrict__ x,
                                              float*       __restrict__ y) {
    int wid  = (blockIdx.x * blockDim.x + threadIdx.x) >> 6;
    int lane = threadIdx.x & 63;
    int nw   = (gridDim.x * blockDim.x) >> 6;
    for (int e = wid; e < NEDGES; e += nw) {
        int   r = rows[e];
        int   c = cols[e];
        float v = vals[e];
        unsafeAtomicAdd(&y[r * DIM + lane], v * x[c * DIM + lane]);
    }
}

__global__ __launch_bounds__(256) void k_accum(const float4* __restrict__ src,
                                               float4* __restrict__ dst, int first) {
    const int n = NGROUPS * DIM / 4;
    int i = blockIdx.x * blockDim.x + threadIdx.x;
    int s = gridDim.x * blockDim.x;
    if (first) { for (; i < n; i += s) dst[i] = src[i]; }
    else {
        for (; i < n; i += s) {
            float4 a = dst[i], b = src[i];
            a.x += b.x; a.y += b.y; a.z += b.z; a.w += b.w;
            dst[i] = a;
        }
    }
}

__global__ __launch_bounds__(256) void k_final(const float4* __restrict__ g,
                                               float4* __restrict__ out) {
    const int n = NGROUPS * DIM / 4;
    int i = blockIdx.x * blockDim.x + threadIdx.x;
    int s = gridDim.x * blockDim.x;
    for (; i < n; i += s) {
        float4 a = out[i], b = g[i];
        out[i] = make_float4((a.x + b.x) * 0.25f, (a.y + b.y) * 0.25f,
                             (a.z + b.z) * 0.25f, (a.w + b.w) * 0.25f);
    }
}

// ===========================================================================

extern "C" void kernel_launch(void* const* d_in, const int* in_sizes, int n_in,
                              void* d_out, int out_size, void* d_ws, size_t ws_size,
                              hipStream_t stream) {
    const float* groups = (const float*)d_in[0];
    const float* items  = (const float*)d_in[1];
    const float* vals   = (const float*)d_in[2];
    const int*   rows   = (const int*)d_in[3];
    const int*   cols   = (const int*)d_in[4];
    float* out = (float*)d_out;

    const int NB = (NNODES + 255) / 256;              // 586 blocks

    // ws layout (float units) — regions kept f32-sized so the fallback path
    // (f32 x-buffers) fits the same layout; bf16 tables use the low half.
    size_t off = 0;
    float* x1     = (float*)d_ws;               off += (size_t)NNODES * DIM;
    float* x2     = (float*)d_ws + off;         off += (size_t)NNODES * DIM;
    int*   cnt    = (int*)((float*)d_ws + off); off += NNODES;
    int*   rowptr = (int*)((float*)d_ws + off); off += NNODES + 4;
    int*   bsum   = (int*)((float*)d_ws + off); off += 1024;
    int*   boff   = (int*)((float*)d_ws + off); off += 1024;
    int2*  scv    = (int2*)((float*)d_ws + off); off += (size_t)NEDGES * 2; // 8B-aligned
    float* x0     = (float*)d_ws + off;         off += (size_t)NNODES * DIM / 2; // bf16 table
    size_t needed = off * sizeof(float);

    ushort* x0b = (ushort*)x0;
    ushort* x1b = (ushort*)x1;
    ushort* x2b = (ushort*)x2;
    // rank[] lives only between hist and scatter; x2 region is written
    // only by the layer-2 SpMM (after scatter) — alias, no ws growth.
    int* rank = (int*)x2;

    dim3 blk(256);

    if (ws_size >= needed) {
        // ---- CSR build (atomic-free permute via counting-sort ranks) ----
        hipMemsetAsync(cnt, 0, (size_t)NNODES * sizeof(int), stream);
        // 2048 blocks = 524288 threads = exact resident capacity (256 CU x 2048):
        // max in-flight atomics for the latency-bound hist phase.
        k_conv_hist<<<2048, blk, 0, stream>>>((const float4*)groups, (const float4*)items,
                                              (ushort4*)x0b, (const int4*)rows,
                                              cnt, (int4*)rank);
        k_bsum<<<NB, blk, 0, stream>>>(cnt, bsum);
        k_scanb<<<1, dim3(1024), 0, stream>>>(bsum, boff, NB);
        k_rowptr<<<NB, blk, 0, stream>>>(cnt, boff, rowptr);
        k_scatter<<<2048, blk, 0, stream>>>((const int4*)rows, (const int4*)cols,
                                            (const float4*)vals, (const int4*)rank,
                                            rowptr, scv);

        // ---- 3 gather layers (bf16 gathers), fused output accumulation ----
        k_spmm_csr<1><<<NNODES / 4, blk, 0, stream>>>(rowptr, scv, x0b,
                                                      (const float4*)groups, x1b,
                                                      (float4*)out);
        k_spmm_csr<2><<<NNODES / 4, blk, 0, stream>>>(rowptr, scv, x1b,
                                                      (const float4*)groups, x2b,
                                                      (float4*)out);
        k_spmm_csr<3><<<NGROUPS / 4, blk, 0, stream>>>(rowptr, scv, x2b,
                                                       (const float4*)groups, nullptr,
                                                       (float4*)out);
    } else {
        // ---- fallback: proven atomic-scatter path (f32) ----
        float* xA = x1;
        float* xB = x2;
        k_concat<<<2048, blk, 0, stream>>>((const float4*)groups, (const float4*)items,
                                           (float4*)xA);
        for (int l = 0; l < 3; ++l) {
            k_zero<<<2048, blk, 0, stream>>>((float4*)xB, NNODES * DIM / 4);
            k_spmm<<<4096, blk, 0, stream>>>(rows, cols, vals, xA, xB);
            k_accum<<<512, blk, 0, stream>>>((const float4*)xB, (float4*)out, l == 0);
            float* t = xA; xA = xB; xB = t;
        }
        k_final<<<512, blk, 0, stream>>>((const float4*)groups, (float4*)out);
    }
}